// Round 7
// baseline (375.593 us; speedup 1.0000x reference)
//
#include <hip/hip_runtime.h>

typedef unsigned short u16;
typedef __attribute__((ext_vector_type(8))) short v8s;   // 8 x bf16 (4 VGPRs)
typedef __attribute__((ext_vector_type(4))) float v4f;   // MFMA 16x16 accumulator

#define S_LEN  2048
#define NHEADS 16
#define DHEAD  64
#define EMB    1024

#if __has_builtin(__builtin_amdgcn_exp2f)
#define EXP2F __builtin_amdgcn_exp2f
#else
#define EXP2F exp2f
#endif

__device__ __forceinline__ u16 f32_bf16(float f) {
  union { float f; unsigned u; } x; x.f = f;
  unsigned r = x.u + 0x7fffu + ((x.u >> 16) & 1u);   // RNE
  return (u16)(r >> 16);
}

__device__ __forceinline__ void async16(const void* g, void* l) {
  // global -> LDS direct DMA, 16B per lane; LDS dest = wave-uniform base + lane*16
  __builtin_amdgcn_global_load_lds(
      (const __attribute__((address_space(1))) unsigned int*)g,
      (__attribute__((address_space(3))) unsigned int*)l, 16, 0, 0);
}

// ---- fp32 -> bf16 conversion, all 7 tensors in one launch ----
__global__ __launch_bounds__(256) void cvt_all(
    const float4* __restrict__ s0, const float4* __restrict__ s1,
    const float4* __restrict__ s2, const float4* __restrict__ s3,
    const float4* __restrict__ s4, const float4* __restrict__ s5,
    const float4* __restrict__ s6,
    ushort4* __restrict__ d0, ushort4* __restrict__ d1,
    ushort4* __restrict__ d2, ushort4* __restrict__ d3,
    ushort4* __restrict__ d4, ushort4* __restrict__ d5,
    ushort4* __restrict__ d6, int nbig, int nsmall) {
  const int y = blockIdx.y;
  const float4* s; ushort4* d;
  switch (y) {
    case 0: s = s0; d = d0; break;  case 1: s = s1; d = d1; break;
    case 2: s = s2; d = d2; break;  case 3: s = s3; d = d3; break;
    case 4: s = s4; d = d4; break;  case 5: s = s5; d = d5; break;
    default: s = s6; d = d6; break;
  }
  const int n4 = (y < 3) ? nbig : nsmall;
  for (int i = blockIdx.x * 256 + threadIdx.x; i < n4; i += gridDim.x * 256) {
    const float4 v = s[i];
    ushort4 o;
    o.x = f32_bf16(v.x); o.y = f32_bf16(v.y);
    o.z = f32_bf16(v.z); o.w = f32_bf16(v.w);
    d[i] = o;
  }
}

// ============================================================================
// 128x128 tile, BK=64, 512 threads / 8 waves (2Mx4N, 64x32 per wave),
// 64 KiB LDS -> 2 blocks/CU = 4 waves/SIMD. 2-phase K-loop, stage-at-top.
// (Round-5 configuration verbatim -- best measured: 82.0us, MfmaUtil 25%.)
// ============================================================================
template <int MODE>
__global__ __launch_bounds__(512, 2) void gemm2ph(
    const u16* __restrict__ A, const u16* __restrict__ W0,
    const u16* __restrict__ W1, const u16* __restrict__ W2,
    u16* __restrict__ Cq, u16* __restrict__ Ck, u16* __restrict__ Cv,
    float* __restrict__ Cf, int mtiles) {
  const int K = 1024;
  const int NKT = 16;                          // K / 64
  __shared__ __align__(16) u16 lA[2][128 * 64];   // 2 x 16 KB
  __shared__ __align__(16) u16 lB[2][128 * 64];   // total 64 KiB
  const int t = threadIdx.x;
  const int lane = t & 63, wv = t >> 6;
  const int wm = wv >> 2, wn = wv & 3;         // 2M x 4N waves, 64x32/wave
  const int qr = lane >> 4, cl = lane & 15;

  // Round-2 mapping: each XCD-residue owns exactly one n-panel -> W L2-resident
  const int nwg = gridDim.x;
  const int sid = (blockIdx.x & 7) * (nwg >> 3) + (blockIdx.x >> 3);
  const int bm = sid % mtiles, bn = sid / mtiles;
  const int m0 = bm << 7, n0 = bn << 7;
  const int sec = (MODE == 0) ? (m0 >> 13) : 0;
  const u16* W =
      (MODE == 0) ? ((sec == 0) ? W0 : (sec == 1) ? W1 : W2) : W0;

  v4f acc[4][2];
#pragma unroll
  for (int i = 0; i < 4; ++i)
#pragma unroll
    for (int j = 0; j < 2; ++j) acc[i][j] = (v4f){0.f, 0.f, 0.f, 0.f};

  // Per-thread staging source: c = t + u*512 -> row = (t>>3) + u*64 (64%8==0
  // so the chunk swizzle is constant across u), chunk = (t&7) ^ (row&7).
  const int srow = t >> 3;
  const int sw = ((t & 7) ^ (srow & 7)) << 3;   // u16 offset within the row
  const u16* aS[2];
  const u16* bS[2];
#pragma unroll
  for (int u = 0; u < 2; ++u) {
    aS[u] = A + (size_t)(m0 + srow + u * 64) * K + sw;
    bS[u] = W + (size_t)(n0 + srow + u * 64) * K + sw;
  }

  // prologue: stage tile 0 into buf 0
#pragma unroll
  for (int u = 0; u < 2; ++u) async16(aS[u], &lA[0][(t + (u << 9)) << 3]);
#pragma unroll
  for (int u = 0; u < 2; ++u) async16(bS[u], &lB[0][(t + (u << 9)) << 3]);
  __syncthreads();

  for (int kt = 0; kt < NKT; ++kt) {
    const int cur = kt & 1;
    if (kt + 1 < NKT) {                         // stage(t+1) FIRST
      const int off = (kt + 1) << 6;
#pragma unroll
      for (int u = 0; u < 2; ++u)
        async16(aS[u] + off, &lA[1 - cur][(t + (u << 9)) << 3]);
#pragma unroll
      for (int u = 0; u < 2; ++u)
        async16(bS[u] + off, &lB[1 - cur][(t + (u << 9)) << 3]);
    }
    v8s a[4][2], b[2][2];
#pragma unroll
    for (int mf = 0; mf < 4; ++mf)
#pragma unroll
      for (int kh = 0; kh < 2; ++kh) {
        const int R = wm * 64 + mf * 16 + cl;
        a[mf][kh] =
            *(const v8s*)&lA[cur][R * 64 + ((((kh << 2) + qr) ^ (R & 7)) << 3)];
      }
#pragma unroll
    for (int nf = 0; nf < 2; ++nf)
#pragma unroll
      for (int kh = 0; kh < 2; ++kh) {
        const int R = wn * 32 + nf * 16 + cl;
        b[nf][kh] =
            *(const v8s*)&lB[cur][R * 64 + ((((kh << 2) + qr) ^ (R & 7)) << 3)];
      }
    __builtin_amdgcn_s_setprio(1);
#pragma unroll
    for (int kh = 0; kh < 2; ++kh)
#pragma unroll
      for (int mf = 0; mf < 4; ++mf)
#pragma unroll
        for (int nf = 0; nf < 2; ++nf)
          acc[mf][nf] = __builtin_amdgcn_mfma_f32_16x16x32_bf16(
              a[mf][kh], b[nf][kh], acc[mf][nf], 0, 0, 0);
    __builtin_amdgcn_s_setprio(0);
    __syncthreads();   // drains vmcnt(0): stage(t+1) complete; buf flip safe
  }

  // ---- epilogue ----
  if constexpr (MODE == 0) {
    u16* C = (sec == 0) ? Cq : (sec == 1) ? Ck : Cv;
#pragma unroll
    for (int mf = 0; mf < 4; ++mf)
#pragma unroll
      for (int nf = 0; nf < 2; ++nf)
#pragma unroll
        for (int r = 0; r < 4; ++r) {
          const int mloc = (m0 & 8191) + wm * 64 + mf * 16 + qr * 4 + r;
          const int n = n0 + wn * 32 + nf * 16 + cl;
          const int bb = mloc >> 11, s = mloc & (S_LEN - 1);
          const int h = n >> 6, d = n & (DHEAD - 1);
          const size_t idx =
              (sec < 2) ? (((size_t)bb * NHEADS + h) * S_LEN + s) * DHEAD + d
                        : (((size_t)bb * NHEADS + h) * DHEAD + d) * S_LEN + s;
          C[idx] = f32_bf16(acc[mf][nf][r]);
        }
  } else {
#pragma unroll
    for (int mf = 0; mf < 4; ++mf)
#pragma unroll
      for (int nf = 0; nf < 2; ++nf)
#pragma unroll
        for (int r = 0; r < 4; ++r) {
          const int m = m0 + wm * 64 + mf * 16 + qr * 4 + r;
          const int n = n0 + wn * 32 + nf * 16 + cl;
          Cf[(size_t)m * 1024 + n] = acc[mf][nf][r];
        }
  }
}

// ============================================================================
// Causal flash attention, MERGED-PHASE 8-wave blocks (new this round).
// Qp/Kp: [B,H,S,D]; VpT: [B,H,D,S]. 512 blocks x 512 threads.
// Block = (column, pair). Waves 0-3 process q-tile (15-pair) [heavy], waves
// 4-7 process q-tile (pair) [light], CONCURRENTLY over ONE shared K/V stream:
// the light tile's key range [0, 2*pair+2) is a subset of the heavy range
// [0, 32-2*pair), so K/V are staged ONCE (was: twice, one per phase) and the
// block runs nkt = 32-2*pair barrier-iterations (was 34).  nkt is
// block-uniform (pair); per-wave early-out is the wave-uniform `continue`
// (skips compute only, never a barrier).
// Gains vs round-5 attn: 4 waves/SIMD (was 2, the proven R5 lever), -26%
// staging traffic, -6..-47% iterations. LDS: 2x8K K + 2x8V + 8x4 pb = 64KB
// -> 2 blocks/CU.  Double-buffered, stage-at-top (R2/R5 sync pattern).
// ============================================================================
__global__ __launch_bounds__(512, 2) void attn_causal(
    const u16* __restrict__ Qp, const u16* __restrict__ Kp,
    const u16* __restrict__ VpT, u16* __restrict__ Out) {
  __shared__ __align__(16) u16 lK[2][64 * 64];  // chunk(key,dc)=key*8+(dc^(key&7))
  __shared__ __align__(16) u16 lV[2][64 * 64];  // chunk(d,kc)=d*8+(kc^(d&7))
  __shared__ __align__(16) u16 pb[8][32 * 64];  // per-wave P scratch
  const int t = threadIdx.x;
  const int lane = t & 63, w = t >> 6;          // w = 0..7
  const int qr = lane >> 4, cl = lane & 15;
  // id = xcd + 8*(pair + 8*colgroup): all 8 pairs of 8 columns share an XCD
  const int id = blockIdx.x;
  const int col = (id & 7) + ((id >> 6) << 3);   // 0..63 = h + 16*b
  const int pair = (id >> 3) & 7;
  const int h = col & 15, b = col >> 4;
  const size_t bh = ((size_t)b * NHEADS + h) * S_LEN * DHEAD;
  const u16* Qb = Qp + bh;
  const u16* Kb = Kp + bh;
  const u16* Vb = VpT + bh;   // [d][s], row stride S_LEN

  v8s vone;
#pragma unroll
  for (int j = 0; j < 8; ++j) vone[j] = (short)0x3F80;   // bf16 1.0
  const float SC = 0.125f * 1.4426950408889634f;         // (1/8)*log2(e)

  // stage 64-key tile TILE of K and V into slot SL: 512 threads x 1 chunk each
#define STAGE_T(TILE, SL)                                                     \
  do {                                                                        \
    const int kn_ = (TILE) << 6;                                              \
    const int r_ = t >> 3, c_ = (t & 7) ^ (r_ & 7);                           \
    async16(Kb + (size_t)(kn_ + r_) * DHEAD + c_ * 8, &lK[SL][t * 8]);        \
    async16(Vb + (size_t)r_ * S_LEN + kn_ + c_ * 8, &lV[SL][t * 8]);          \
  } while (0)

  const int qt = (w < 4) ? (15 - pair) : pair;   // heavy | light tile
  const int q0 = qt << 7;
  const int wr0 = q0 + (w & 3) * 32;             // this wave's first q-row
  const int nkt = 32 - 2 * pair;                 // block-uniform (heavy range)

  v8s aq[2][2];
#pragma unroll
  for (int mf = 0; mf < 2; ++mf)
#pragma unroll
    for (int kf = 0; kf < 2; ++kf)
      aq[mf][kf] = *(const v8s*)(Qb + (size_t)(wr0 + mf * 16 + cl) * DHEAD +
                                 kf * 32 + qr * 8);

  v4f o[2][4], lac[2];
#pragma unroll
  for (int mf = 0; mf < 2; ++mf) {
    lac[mf] = (v4f){0.f, 0.f, 0.f, 0.f};
#pragma unroll
    for (int nf = 0; nf < 4; ++nf) o[mf][nf] = (v4f){0.f, 0.f, 0.f, 0.f};
  }

  STAGE_T(0, 0);   // prologue

  for (int kt = 0; kt < nkt; ++kt) {
    const int k0 = kt << 6;
    const int cb = kt & 1;
    __syncthreads();   // tile kt landed in slot cb; slot 1-cb free
    if (kt + 1 < nkt) STAGE_T(kt + 1, 1 - cb);
    if (k0 > wr0 + 31) continue;   // wave-uniform: tile fully above diagonal
                                   // (also ends light waves' range early)

    // ---- S = Q K^T  (16 MFMA) ----
    v4f sacc[2][4];
#pragma unroll
    for (int mf = 0; mf < 2; ++mf)
#pragma unroll
      for (int ni = 0; ni < 4; ++ni) sacc[mf][ni] = (v4f){0.f, 0.f, 0.f, 0.f};
#pragma unroll
    for (int kf = 0; kf < 2; ++kf)
#pragma unroll
      for (int ni = 0; ni < 4; ++ni) {
        const v8s bk = *(const v8s*)&lK[cb][((ni * 16 + cl) * 8 +
                                            (((kf << 2) + qr) ^ (cl & 7))) * 8];
        sacc[0][ni] = __builtin_amdgcn_mfma_f32_16x16x32_bf16(aq[0][kf], bk,
                                                              sacc[0][ni], 0, 0, 0);
        sacc[1][ni] = __builtin_amdgcn_mfma_f32_16x16x32_bf16(aq[1][kf], bk,
                                                              sacc[1][ni], 0, 0, 0);
      }

    // ---- exp2, (diagonal-only) mask, truncate-to-bf16, store P ----
#pragma unroll
    for (int mf = 0; mf < 2; ++mf) {
      const int rowb0 = wr0 + mf * 16;
      if (k0 + 63 <= rowb0) {        // wave-uniform: no masking on this frag
#pragma unroll
        for (int ni = 0; ni < 4; ++ni) {
          const int kc = ni * 2 + (cl >> 3);
#pragma unroll
          for (int r = 0; r < 4; ++r) {
            const float e = EXP2F(sacc[mf][ni][r] * SC);
            pb[w][((kc * 32 + mf * 16 + r * 4 + qr) << 3) + (cl & 7)] =
                (u16)(__float_as_uint(e) >> 16);
          }
        }
      } else {                        // diagonal: mask then exp
        const int rowb = rowb0 + qr * 4;
#pragma unroll
        for (int ni = 0; ni < 4; ++ni) {
          const int colk = k0 + ni * 16 + cl;
          const int kc = ni * 2 + (cl >> 3);
#pragma unroll
          for (int r = 0; r < 4; ++r) {
            float e = EXP2F(sacc[mf][ni][r] * SC);
            if (colk > rowb + r) e = 0.f;
            pb[w][((kc * 32 + mf * 16 + r * 4 + qr) << 3) + (cl & 7)] =
                (u16)(__float_as_uint(e) >> 16);
          }
        }
      }
    }

    // ---- O += P V, l += P 1  (wave-local pb: lgkmcnt ordering only) ----
#pragma unroll
    for (int kf = 0; kf < 2; ++kf) {
      const int kc = (kf << 2) + qr;
      const int sig0 = ((cl & 3) << 2) + (cl >> 2);
      const v8s ap0 = *(const v8s*)&pb[w][((kc * 32 + sig0) << 3)];
      const v8s ap1 = *(const v8s*)&pb[w][((kc * 32 + 16 + sig0) << 3)];
      lac[0] = __builtin_amdgcn_mfma_f32_16x16x32_bf16(ap0, vone, lac[0], 0, 0, 0);
      lac[1] = __builtin_amdgcn_mfma_f32_16x16x32_bf16(ap1, vone, lac[1], 0, 0, 0);
#pragma unroll
      for (int nf = 0; nf < 4; ++nf) {
        const v8s bv = *(const v8s*)&lV[cb][((nf * 16 + cl) * 8 +
                                            (kc ^ (cl & 7))) * 8];
        o[0][nf] = __builtin_amdgcn_mfma_f32_16x16x32_bf16(ap0, bv, o[0][nf], 0, 0, 0);
        o[1][nf] = __builtin_amdgcn_mfma_f32_16x16x32_bf16(ap1, bv, o[1][nf], 0, 0, 0);
      }
    }
  }

  // epilogue: O / l
#pragma unroll
  for (int mf = 0; mf < 2; ++mf) {
    float inv[4];
#pragma unroll
    for (int r = 0; r < 4; ++r) inv[r] = 1.0f / lac[mf][r];
#pragma unroll
    for (int nf = 0; nf < 4; ++nf)
#pragma unroll
      for (int r = 0; r < 4; ++r) {
        const int row = wr0 + mf * 16 + qr * 4 + r;
        const int colo = h * DHEAD + nf * 16 + cl;
        Out[((size_t)b * S_LEN + row) * EMB + colo] = f32_bf16(o[mf][nf][r] * inv[r]);
      }
  }
#undef STAGE_T
}

extern "C" void kernel_launch(void* const* d_in, const int* in_sizes, int n_in,
                              void* d_out, int out_size, void* d_ws, size_t ws_size,
                              hipStream_t stream) {
  (void)in_sizes; (void)n_in; (void)out_size; (void)ws_size;
  const float* q  = (const float*)d_in[0];
  const float* k  = (const float*)d_in[1];
  const float* v  = (const float*)d_in[2];
  // d_in[3] = causal mask (int32) — implemented analytically, not read
  const float* wq = (const float*)d_in[4];
  const float* wk = (const float*)d_in[5];
  const float* wv = (const float*)d_in[6];
  const float* wo = (const float*)d_in[7];
  float* out = (float*)d_out;   // reference output dtype is float32

  const size_t MT = (size_t)4 * S_LEN * EMB;   // 8,388,608 elems
  const size_t WT = (size_t)EMB * EMB;         // 1,048,576 elems
  u16* p = (u16*)d_ws;
  u16* xq = p; p += MT;     // xq|xk|xv contiguous: A-matrix of the fused QKV GEMM
  u16* xk = p; p += MT;
  u16* xv = p; p += MT;
  u16* wqb = p; p += WT;
  u16* wkb = p; p += WT;
  u16* wvb = p; p += WT;
  u16* wob = p; p += WT;
  u16* Qp = p; p += MT;
  u16* Kp = p; p += MT;
  u16* Vp = p; p += MT;
  u16* Ao = xq;          // xq dead after projection GEMM — reuse

  const dim3 blk(256);
  hipLaunchKernelGGL(cvt_all, dim3(512, 7), blk, 0, stream,
                     (const float4*)q, (const float4*)k, (const float4*)v,
                     (const float4*)wq, (const float4*)wk, (const float4*)wv,
                     (const float4*)wo,
                     (ushort4*)xq, (ushort4*)xk, (ushort4*)xv,
                     (ushort4*)wqb, (ushort4*)wkb, (ushort4*)wvb, (ushort4*)wob,
                     (int)(MT / 4), (int)(WT / 4));
  // 192 m-tiles x 8 n-tiles = 1536 blocks; 512 thr, 2 blocks/CU -> 3 rounds
  hipLaunchKernelGGL((gemm2ph<0>), dim3(1536), dim3(512), 0, stream,
                     xq, wqb, wkb, wvb, Qp, Kp, Vp, (float*)nullptr, 192);
  // merged-phase attn: 512 blocks x 512 threads, 2 blocks/CU
  hipLaunchKernelGGL(attn_causal, dim3(512), dim3(512), 0, stream,
                     Qp, Kp, Vp, Ao);
  // 64 m-tiles x 8 n-tiles = 512 blocks; 512 thr, 2 blocks/CU -> 1 round
  hipLaunchKernelGGL((gemm2ph<1>), dim3(512), dim3(512), 0, stream,
                     Ao, wob, (const u16*)nullptr, (const u16*)nullptr,
                     (u16*)nullptr, (u16*)nullptr, (u16*)nullptr, out, 64);
}

// Round 8
// 360.989 us; speedup vs baseline: 1.0405x; 1.0405x over previous
//
#include <hip/hip_runtime.h>

typedef unsigned short u16;
typedef __attribute__((ext_vector_type(8))) short v8s;   // 8 x bf16 (4 VGPRs)
typedef __attribute__((ext_vector_type(4))) float v4f;   // MFMA 16x16 accumulator

#define S_LEN  2048
#define NHEADS 16
#define DHEAD  64
#define EMB    1024

#if __has_builtin(__builtin_amdgcn_exp2f)
#define EXP2F __builtin_amdgcn_exp2f
#else
#define EXP2F exp2f
#endif

__device__ __forceinline__ u16 f32_bf16(float f) {
  union { float f; unsigned u; } x; x.f = f;
  unsigned r = x.u + 0x7fffu + ((x.u >> 16) & 1u);   // RNE
  return (u16)(r >> 16);
}

__device__ __forceinline__ void async16(const void* g, void* l) {
  // global -> LDS direct DMA, 16B per lane; LDS dest = wave-uniform base + lane*16
  __builtin_amdgcn_global_load_lds(
      (const __attribute__((address_space(1))) unsigned int*)g,
      (__attribute__((address_space(3))) unsigned int*)l, 16, 0, 0);
}

// ---- fp32 -> bf16 conversion, WEIGHTS ONLY (q/k/v conversion fused into
// gemm_qkv A-staging this round) ----
__global__ __launch_bounds__(256) void cvt_w(
    const float4* __restrict__ s0, const float4* __restrict__ s1,
    const float4* __restrict__ s2, const float4* __restrict__ s3,
    ushort4* __restrict__ d0, ushort4* __restrict__ d1,
    ushort4* __restrict__ d2, ushort4* __restrict__ d3, int n4) {
  const int y = blockIdx.y;
  const float4* s; ushort4* d;
  switch (y) {
    case 0: s = s0; d = d0; break;  case 1: s = s1; d = d1; break;
    case 2: s = s2; d = d2; break;  default: s = s3; d = d3; break;
  }
  for (int i = blockIdx.x * 256 + threadIdx.x; i < n4; i += gridDim.x * 256) {
    const float4 v = s[i];
    ushort4 o;
    o.x = f32_bf16(v.x); o.y = f32_bf16(v.y);
    o.z = f32_bf16(v.z); o.w = f32_bf16(v.w);
    d[i] = o;
  }
}

// ============================================================================
// 128x128 tile, BK=64, 512 threads / 8 waves (2Mx4N, 64x32 per wave),
// 64 KiB LDS -> 2 blocks/CU = 4 waves/SIMD. 2-phase K-loop, stage-at-top.
// (Round-5 structure -- best measured: 82.0us, MfmaUtil 25%.)
//
// MODE 0 (NEW): A is read DIRECTLY from the fp32 q/k/v inputs with fused
//   fp32->bf16 conversion: T14 split -- issue 4x global_load_dwordx4 at the
//   TOP of the body (latency hidden under ds_read+MFMA), cvt+ds_write_b128
//   into lA[1-cur] AFTER the MFMA block, before the barrier. B (weights,
//   pre-converted bf16) keeps the DMA path. Eliminates the 150MB q/k/v
//   conversion pass entirely.
// MODE 1: output projection, A = Ao bf16 via DMA (unchanged R5 path),
//   C fp32 row-major [M,1024].
//
// Round-2 block mapping: each XCD-residue owns one n-panel -> W L2-resident.
// ============================================================================
template <int MODE>
__global__ __launch_bounds__(512, 2) void gemm2ph(
    const float* __restrict__ F0, const float* __restrict__ F1,
    const float* __restrict__ F2,            // MODE 0: fp32 A sources (q,k,v)
    const u16* __restrict__ Abf,             // MODE 1: bf16 A
    const u16* __restrict__ W0, const u16* __restrict__ W1,
    const u16* __restrict__ W2,
    u16* __restrict__ Cq, u16* __restrict__ Ck, u16* __restrict__ Cv,
    float* __restrict__ Cf, int mtiles) {
  const int K = 1024;
  const int NKT = 16;                          // K / 64
  __shared__ __align__(16) u16 lA[2][128 * 64];   // 2 x 16 KB
  __shared__ __align__(16) u16 lB[2][128 * 64];   // total 64 KiB
  const int t = threadIdx.x;
  const int lane = t & 63, wv = t >> 6;
  const int wm = wv >> 2, wn = wv & 3;         // 2M x 4N waves, 64x32/wave
  const int qr = lane >> 4, cl = lane & 15;

  // Round-2 mapping: each XCD-residue owns exactly one n-panel -> W L2-resident
  const int nwg = gridDim.x;
  const int sid = (blockIdx.x & 7) * (nwg >> 3) + (blockIdx.x >> 3);
  const int bm = sid % mtiles, bn = sid / mtiles;
  const int m0 = bm << 7, n0 = bn << 7;
  const int sec = (MODE == 0) ? (m0 >> 13) : 0;
  const u16* W =
      (MODE == 0) ? ((sec == 0) ? W0 : (sec == 1) ? W1 : W2) : W0;

  v4f acc[4][2];
#pragma unroll
  for (int i = 0; i < 4; ++i)
#pragma unroll
    for (int j = 0; j < 2; ++j) acc[i][j] = (v4f){0.f, 0.f, 0.f, 0.f};

  // Per-thread staging geometry: thread t covers rows srow, srow+64 with the
  // 16B chunk at swizzled slot (t&7)^(row&7) (constant across u since 64%8==0).
  const int srow = t >> 3;
  const int swe = ((t & 7) ^ (srow & 7)) << 3;   // ELEMENT offset within row

  const float* fS[2];   // MODE 0: fp32 sources
  const u16* aS[2];     // MODE 1: bf16 source
  const u16* bS[2];
  if constexpr (MODE == 0) {
    const int mloc = m0 & 8191;
    const float* Fs = (sec == 0) ? F0 : (sec == 1) ? F1 : F2;
#pragma unroll
    for (int u = 0; u < 2; ++u)
      fS[u] = Fs + (size_t)(mloc + srow + u * 64) * K + swe;
  } else {
#pragma unroll
    for (int u = 0; u < 2; ++u)
      aS[u] = Abf + (size_t)(m0 + srow + u * 64) * K + swe;
  }
#pragma unroll
  for (int u = 0; u < 2; ++u)
    bS[u] = W + (size_t)(n0 + srow + u * 64) * K + swe;

#define CVT_WRITE(U, BUF, LO, HI)                                             \
  do {                                                                        \
    v8s pk_;                                                                  \
    pk_[0] = (short)f32_bf16((LO).x); pk_[1] = (short)f32_bf16((LO).y);       \
    pk_[2] = (short)f32_bf16((LO).z); pk_[3] = (short)f32_bf16((LO).w);       \
    pk_[4] = (short)f32_bf16((HI).x); pk_[5] = (short)f32_bf16((HI).y);       \
    pk_[6] = (short)f32_bf16((HI).z); pk_[7] = (short)f32_bf16((HI).w);       \
    *(v8s*)&lA[BUF][(t + ((U) << 9)) << 3] = pk_;                             \
  } while (0)

  // ---- prologue: stage tile 0 into buf 0 ----
  if constexpr (MODE == 0) {
#pragma unroll
    for (int u = 0; u < 2; ++u) {
      const float4 lo = *(const float4*)(fS[u]);
      const float4 hi = *(const float4*)(fS[u] + 4);
      CVT_WRITE(u, 0, lo, hi);
    }
  } else {
#pragma unroll
    for (int u = 0; u < 2; ++u) async16(aS[u], &lA[0][(t + (u << 9)) << 3]);
  }
#pragma unroll
  for (int u = 0; u < 2; ++u) async16(bS[u], &lB[0][(t + (u << 9)) << 3]);
  __syncthreads();

  for (int kt = 0; kt < NKT; ++kt) {
    const int cur = kt & 1;
    float4 fa0[2], fa1[2];
    if (kt + 1 < NKT) {                         // issue stage(t+1) FIRST
      const int off = (kt + 1) << 6;
      if constexpr (MODE == 0) {
#pragma unroll
        for (int u = 0; u < 2; ++u) {
          fa0[u] = *(const float4*)(fS[u] + off);
          fa1[u] = *(const float4*)(fS[u] + off + 4);
        }
      } else {
#pragma unroll
        for (int u = 0; u < 2; ++u)
          async16(aS[u] + off, &lA[1 - cur][(t + (u << 9)) << 3]);
      }
#pragma unroll
      for (int u = 0; u < 2; ++u)
        async16(bS[u] + off, &lB[1 - cur][(t + (u << 9)) << 3]);
    }
    v8s a[4][2], b[2][2];
#pragma unroll
    for (int mf = 0; mf < 4; ++mf)
#pragma unroll
      for (int kh = 0; kh < 2; ++kh) {
        const int R = wm * 64 + mf * 16 + cl;
        a[mf][kh] =
            *(const v8s*)&lA[cur][R * 64 + ((((kh << 2) + qr) ^ (R & 7)) << 3)];
      }
#pragma unroll
    for (int nf = 0; nf < 2; ++nf)
#pragma unroll
      for (int kh = 0; kh < 2; ++kh) {
        const int R = wn * 32 + nf * 16 + cl;
        b[nf][kh] =
            *(const v8s*)&lB[cur][R * 64 + ((((kh << 2) + qr) ^ (R & 7)) << 3)];
      }
    __builtin_amdgcn_s_setprio(1);
#pragma unroll
    for (int kh = 0; kh < 2; ++kh)
#pragma unroll
      for (int mf = 0; mf < 4; ++mf)
#pragma unroll
        for (int nf = 0; nf < 2; ++nf)
          acc[mf][nf] = __builtin_amdgcn_mfma_f32_16x16x32_bf16(
              a[mf][kh], b[nf][kh], acc[mf][nf], 0, 0, 0);
    __builtin_amdgcn_s_setprio(0);
    if constexpr (MODE == 0) {                  // write-late: cvt + ds_write
      if (kt + 1 < NKT) {
#pragma unroll
        for (int u = 0; u < 2; ++u) CVT_WRITE(u, 1 - cur, fa0[u], fa1[u]);
      }
    }
    __syncthreads();   // drains vmcnt+lgkm: stage(t+1) complete; flip safe
  }
#undef CVT_WRITE

  // ---- epilogue ----
  if constexpr (MODE == 0) {
    u16* C = (sec == 0) ? Cq : (sec == 1) ? Ck : Cv;
#pragma unroll
    for (int mf = 0; mf < 4; ++mf)
#pragma unroll
      for (int nf = 0; nf < 2; ++nf)
#pragma unroll
        for (int r = 0; r < 4; ++r) {
          const int mloc = (m0 & 8191) + wm * 64 + mf * 16 + qr * 4 + r;
          const int n = n0 + wn * 32 + nf * 16 + cl;
          const int bb = mloc >> 11, s = mloc & (S_LEN - 1);
          const int h = n >> 6, d = n & (DHEAD - 1);
          const size_t idx =
              (sec < 2) ? (((size_t)bb * NHEADS + h) * S_LEN + s) * DHEAD + d
                        : (((size_t)bb * NHEADS + h) * DHEAD + d) * S_LEN + s;
          C[idx] = f32_bf16(acc[mf][nf][r]);
        }
  } else {
#pragma unroll
    for (int mf = 0; mf < 4; ++mf)
#pragma unroll
      for (int nf = 0; nf < 2; ++nf)
#pragma unroll
        for (int r = 0; r < 4; ++r) {
          const int m = m0 + wm * 64 + mf * 16 + qr * 4 + r;
          const int n = n0 + wn * 32 + nf * 16 + cl;
          Cf[(size_t)m * 1024 + n] = acc[mf][nf][r];
        }
  }
}

// Causal flash attention, no-max softmax. Qp/Kp: [B,H,S,D]; VpT: [B,H,D,S].
// 512 blocks x 256 threads; block = (column, pair): q-tile (15-pair) then
// (pair) -> exactly 34 K-iterations per block (perfect causal load balance;
// the R7 merged-phase variant broke this balance and regressed -35us).
// QUAD-buffered K/V (2 groups x 2 tiles, 80KB LDS -> 2 blocks/CU): ONE
// barrier per TWO 64-key tiles.  (R4/R5 version verbatim.)
__global__ __launch_bounds__(256, 2) void attn_causal(
    const u16* __restrict__ Qp, const u16* __restrict__ Kp,
    const u16* __restrict__ VpT, u16* __restrict__ Out) {
  __shared__ __align__(16) u16 lK[2][2][64 * 64];  // [grp parity][slot]
  __shared__ __align__(16) u16 lV[2][2][64 * 64];  // chunk(d,kc)=d*8+(kc^(d&7))
  __shared__ __align__(16) u16 pb[4][32 * 64];     // per-wave P
  const int t = threadIdx.x;
  const int lane = t & 63, w = t >> 6;
  const int qr = lane >> 4, cl = lane & 15;
  // id = xcd + 8*(pair + 8*colgroup): all 8 pairs of 8 columns share an XCD
  const int id = blockIdx.x;
  const int col = (id & 7) + ((id >> 6) << 3);   // 0..63 = h + 16*b
  const int pair = (id >> 3) & 7;
  const int h = col & 15, b = col >> 4;
  const size_t bh = ((size_t)b * NHEADS + h) * S_LEN * DHEAD;
  const u16* Qb = Qp + bh;
  const u16* Kb = Kp + bh;
  const u16* Vb = VpT + bh;   // [d][s], row stride S_LEN

  v8s vone;
#pragma unroll
  for (int j = 0; j < 8; ++j) vone[j] = (short)0x3F80;   // bf16 1.0
  const float SC = 0.125f * 1.4426950408889634f;         // (1/8)*log2(e)

  // stage 64-key tile TILE of K and V into (GP, SL)
#define STAGE_T(TILE, GP, SL)                                                 \
  do {                                                                        \
    const int kn_ = (TILE) << 6;                                              \
    _Pragma("unroll") for (int i_ = 0; i_ < 2; ++i_) {                        \
      const int c_ = t + (i_ << 8);                                           \
      const int krow_ = c_ >> 3, kdc_ = (c_ & 7) ^ (krow_ & 7);               \
      async16(Kb + (size_t)(kn_ + krow_) * DHEAD + kdc_ * 8,                  \
              &lK[GP][SL][(w * 64 + (i_ << 8)) * 8]);                         \
      const int vd_ = c_ >> 3, vkc_ = (c_ & 7) ^ (vd_ & 7);                   \
      async16(Vb + (size_t)vd_ * S_LEN + kn_ + vkc_ * 8,                      \
              &lV[GP][SL][(w * 64 + (i_ << 8)) * 8]);                         \
    }                                                                         \
  } while (0)

  for (int phase = 0; phase < 2; ++phase) {
    const int qt = phase == 0 ? (15 - pair) : pair;   // heavy tile first
    const int q0 = qt << 7;
    const int wr0 = q0 + w * 32;   // this wave's first q-row

    v8s aq[2][2];
#pragma unroll
    for (int mf = 0; mf < 2; ++mf)
#pragma unroll
      for (int kf = 0; kf < 2; ++kf)
        aq[mf][kf] = *(const v8s*)(Qb + (size_t)(wr0 + mf * 16 + cl) * DHEAD +
                                   kf * 32 + qr * 8);

    v4f o[2][4], lac[2];
#pragma unroll
    for (int mf = 0; mf < 2; ++mf) {
      lac[mf] = (v4f){0.f, 0.f, 0.f, 0.f};
#pragma unroll
      for (int nf = 0; nf < 4; ++nf) o[mf][nf] = (v4f){0.f, 0.f, 0.f, 0.f};
    }

    const int ngrp = qt + 1;          // nkt = 2*qt+2 tiles = ngrp groups of 2
    __syncthreads();   // prior phase's LDS reads complete before re-staging
    STAGE_T(0, 0, 0);
    STAGE_T(1, 0, 1);

    for (int g = 0; g < ngrp; ++g) {
      const int gp = g & 1;
      __syncthreads();   // group g's 8 loads landed; buf[1-gp] free
      if (g + 1 < ngrp) {
        STAGE_T(2 * g + 2, 1 - gp, 0);
        STAGE_T(2 * g + 3, 1 - gp, 1);
      }
#pragma unroll
      for (int sl = 0; sl < 2; ++sl) {
        const int kt = 2 * g + sl;
        const int k0 = kt << 6;
        if (k0 > wr0 + 31) continue;   // wave-uniform: fully above diagonal
        const u16* lKc = &lK[gp][sl][0];
        const u16* lVc = &lV[gp][sl][0];

        // ---- S = Q K^T  (16 MFMA) ----
        v4f sacc[2][4];
#pragma unroll
        for (int mf = 0; mf < 2; ++mf)
#pragma unroll
          for (int ni = 0; ni < 4; ++ni) sacc[mf][ni] = (v4f){0.f, 0.f, 0.f, 0.f};
#pragma unroll
        for (int kf = 0; kf < 2; ++kf)
#pragma unroll
          for (int ni = 0; ni < 4; ++ni) {
            const v8s bk = *(const v8s*)&lKc[((ni * 16 + cl) * 8 +
                                             (((kf << 2) + qr) ^ (cl & 7))) * 8];
            sacc[0][ni] = __builtin_amdgcn_mfma_f32_16x16x32_bf16(
                aq[0][kf], bk, sacc[0][ni], 0, 0, 0);
            sacc[1][ni] = __builtin_amdgcn_mfma_f32_16x16x32_bf16(
                aq[1][kf], bk, sacc[1][ni], 0, 0, 0);
          }

        // ---- exp2, (diagonal-only) mask, truncate-to-bf16, store P ----
#pragma unroll
        for (int mf = 0; mf < 2; ++mf) {
          const int rowb0 = wr0 + mf * 16;
          if (k0 + 63 <= rowb0) {        // wave-uniform: no masking here
#pragma unroll
            for (int ni = 0; ni < 4; ++ni) {
              const int kc = ni * 2 + (cl >> 3);
#pragma unroll
              for (int r = 0; r < 4; ++r) {
                const float e = EXP2F(sacc[mf][ni][r] * SC);
                pb[w][((kc * 32 + mf * 16 + r * 4 + qr) << 3) + (cl & 7)] =
                    (u16)(__float_as_uint(e) >> 16);
              }
            }
          } else {                        // diagonal: mask then exp
            const int rowb = rowb0 + qr * 4;
#pragma unroll
            for (int ni = 0; ni < 4; ++ni) {
              const int colk = k0 + ni * 16 + cl;
              const int kc = ni * 2 + (cl >> 3);
#pragma unroll
              for (int r = 0; r < 4; ++r) {
                float e = EXP2F(sacc[mf][ni][r] * SC);
                if (colk > rowb + r) e = 0.f;
                pb[w][((kc * 32 + mf * 16 + r * 4 + qr) << 3) + (cl & 7)] =
                    (u16)(__float_as_uint(e) >> 16);
              }
            }
          }
        }

        // ---- O += P V, l += P 1  (wave-local pb: lgkmcnt ordering only) ----
#pragma unroll
        for (int kf = 0; kf < 2; ++kf) {
          const int kc = (kf << 2) + qr;
          const int sig0 = ((cl & 3) << 2) + (cl >> 2);
          const v8s ap0 = *(const v8s*)&pb[w][((kc * 32 + sig0) << 3)];
          const v8s ap1 = *(const v8s*)&pb[w][((kc * 32 + 16 + sig0) << 3)];
          lac[0] = __builtin_amdgcn_mfma_f32_16x16x32_bf16(ap0, vone, lac[0], 0, 0, 0);
          lac[1] = __builtin_amdgcn_mfma_f32_16x16x32_bf16(ap1, vone, lac[1], 0, 0, 0);
#pragma unroll
          for (int nf = 0; nf < 4; ++nf) {
            const v8s bv = *(const v8s*)&lVc[((nf * 16 + cl) * 8 +
                                             (kc ^ (cl & 7))) * 8];
            o[0][nf] = __builtin_amdgcn_mfma_f32_16x16x32_bf16(ap0, bv, o[0][nf], 0, 0, 0);
            o[1][nf] = __builtin_amdgcn_mfma_f32_16x16x32_bf16(ap1, bv, o[1][nf], 0, 0, 0);
          }
        }
      }
    }

    // epilogue: O / l
#pragma unroll
    for (int mf = 0; mf < 2; ++mf) {
      float inv[4];
#pragma unroll
      for (int r = 0; r < 4; ++r) inv[r] = 1.0f / lac[mf][r];
#pragma unroll
      for (int nf = 0; nf < 4; ++nf)
#pragma unroll
        for (int r = 0; r < 4; ++r) {
          const int row = wr0 + mf * 16 + qr * 4 + r;
          const int colo = h * DHEAD + nf * 16 + cl;
          Out[((size_t)b * S_LEN + row) * EMB + colo] = f32_bf16(o[mf][nf][r] * inv[r]);
        }
    }
  }
#undef STAGE_T
}

extern "C" void kernel_launch(void* const* d_in, const int* in_sizes, int n_in,
                              void* d_out, int out_size, void* d_ws, size_t ws_size,
                              hipStream_t stream) {
  (void)in_sizes; (void)n_in; (void)out_size; (void)ws_size;
  const float* q  = (const float*)d_in[0];
  const float* k  = (const float*)d_in[1];
  const float* v  = (const float*)d_in[2];
  // d_in[3] = causal mask (int32) — implemented analytically, not read
  const float* wq = (const float*)d_in[4];
  const float* wk = (const float*)d_in[5];
  const float* wv = (const float*)d_in[6];
  const float* wo = (const float*)d_in[7];
  float* out = (float*)d_out;   // reference output dtype is float32

  const size_t MT = (size_t)4 * S_LEN * EMB;   // 8,388,608 elems
  const size_t WT = (size_t)EMB * EMB;         // 1,048,576 elems
  u16* p = (u16*)d_ws;
  u16* wqb = p; p += WT;
  u16* wkb = p; p += WT;
  u16* wvb = p; p += WT;
  u16* wob = p; p += WT;
  u16* Qp = p; p += MT;
  u16* Kp = p; p += MT;
  u16* Vp = p; p += MT;
  u16* Ao = p; p += MT;

  // weights-only conversion (q/k/v conversion fused into gemm_qkv)
  hipLaunchKernelGGL(cvt_w, dim3(128, 4), dim3(256), 0, stream,
                     (const float4*)wq, (const float4*)wk, (const float4*)wv,
                     (const float4*)wo,
                     (ushort4*)wqb, (ushort4*)wkb, (ushort4*)wvb, (ushort4*)wob,
                     (int)(WT / 4));
  // fused cvt+QKV projection: 192 m-tiles x 8 n-tiles = 1536 blocks
  hipLaunchKernelGGL((gemm2ph<0>), dim3(1536), dim3(512), 0, stream,
                     q, k, v, (const u16*)nullptr,
                     wqb, wkb, wvb, Qp, Kp, Vp, (float*)nullptr, 192);
  hipLaunchKernelGGL(attn_causal, dim3(512), dim3(256), 0, stream,
                     Qp, Kp, Vp, Ao);
  // output projection: 64 m-tiles x 8 n-tiles = 512 blocks
  hipLaunchKernelGGL((gemm2ph<1>), dim3(512), dim3(512), 0, stream,
                     (const float*)nullptr, (const float*)nullptr,
                     (const float*)nullptr, Ao,
                     wob, (const u16*)nullptr, (const u16*)nullptr,
                     (u16*)nullptr, (u16*)nullptr, (u16*)nullptr, out, 64);
}

// Round 9
// 342.115 us; speedup vs baseline: 1.0979x; 1.0552x over previous
//
#include <hip/hip_runtime.h>

typedef unsigned short u16;
typedef __attribute__((ext_vector_type(8))) short v8s;   // 8 x bf16 (4 VGPRs)
typedef __attribute__((ext_vector_type(4))) float v4f;   // MFMA 16x16 accumulator

#define S_LEN  2048
#define NHEADS 16
#define DHEAD  64
#define EMB    1024

#if __has_builtin(__builtin_amdgcn_exp2f)
#define EXP2F __builtin_amdgcn_exp2f
#else
#define EXP2F exp2f
#endif

__device__ __forceinline__ u16 f32_bf16(float f) {
  union { float f; unsigned u; } x; x.f = f;
  unsigned r = x.u + 0x7fffu + ((x.u >> 16) & 1u);   // RNE
  return (u16)(r >> 16);
}

__device__ __forceinline__ void async16(const void* g, void* l) {
  // global -> LDS direct DMA, 16B per lane; LDS dest = wave-uniform base + lane*16
  __builtin_amdgcn_global_load_lds(
      (const __attribute__((address_space(1))) unsigned int*)g,
      (__attribute__((address_space(3))) unsigned int*)l, 16, 0, 0);
}

// ---- fp32 -> bf16 conversion, all 7 tensors, 8 elems/thread (16B stores) ----
__global__ __launch_bounds__(256) void cvt_all(
    const float4* __restrict__ s0, const float4* __restrict__ s1,
    const float4* __restrict__ s2, const float4* __restrict__ s3,
    const float4* __restrict__ s4, const float4* __restrict__ s5,
    const float4* __restrict__ s6,
    u16* __restrict__ d0, u16* __restrict__ d1,
    u16* __restrict__ d2, u16* __restrict__ d3,
    u16* __restrict__ d4, u16* __restrict__ d5,
    u16* __restrict__ d6, int nbig, int nsmall) {
  const int y = blockIdx.y;
  const float4* s; u16* d;
  switch (y) {
    case 0: s = s0; d = d0; break;  case 1: s = s1; d = d1; break;
    case 2: s = s2; d = d2; break;  case 3: s = s3; d = d3; break;
    case 4: s = s4; d = d4; break;  case 5: s = s5; d = d5; break;
    default: s = s6; d = d6; break;
  }
  const int n8 = (y < 3) ? nbig : nsmall;   // count of 8-elem groups
  for (int i = blockIdx.x * 256 + threadIdx.x; i < n8; i += gridDim.x * 256) {
    const float4 lo = s[2 * i];
    const float4 hi = s[2 * i + 1];
    v8s o;
    o[0] = (short)f32_bf16(lo.x); o[1] = (short)f32_bf16(lo.y);
    o[2] = (short)f32_bf16(lo.z); o[3] = (short)f32_bf16(lo.w);
    o[4] = (short)f32_bf16(hi.x); o[5] = (short)f32_bf16(hi.y);
    o[6] = (short)f32_bf16(hi.z); o[7] = (short)f32_bf16(hi.w);
    *(v8s*)(d + (size_t)i * 8) = o;
  }
}

// ============================================================================
// 128x128 tile, BK=64, **1024 threads / 16 waves** (4Mx4N, 32x32 per wave),
// 64 KiB LDS -> 2 blocks/CU = 32 waves/CU = 8 waves/SIMD (extends the R5 TLP
// lever: 2->4 waves/SIMD was +8%).  2-phase K-loop, stage-at-top, single
// barrier per K-step (best-measured family).  T2 XOR-swizzle (0 conflicts).
// Round-2 mapping: each XCD-residue owns one n-panel -> W L2-resident.
// VGPR must stay <=64 for 2 blocks/CU -- acc is only 2x2xv4f now.
//
// MODE 0: fused QKV projection. A=[xq;xk;xv] [24576,1024]; sec=m0>>13 picks
//         W and output (Cq/Ck: [B,H,S,D] bf16; Cv: [B,H,D,S] bf16).
// MODE 1: output projection, C fp32 row-major [M,1024].
// ============================================================================
template <int MODE>
__global__ __launch_bounds__(1024, 8) void gemm2ph(
    const u16* __restrict__ A, const u16* __restrict__ W0,
    const u16* __restrict__ W1, const u16* __restrict__ W2,
    u16* __restrict__ Cq, u16* __restrict__ Ck, u16* __restrict__ Cv,
    float* __restrict__ Cf, int mtiles) {
  const int K = 1024;
  const int NKT = 16;                          // K / 64
  __shared__ __align__(16) u16 lA[2][128 * 64];   // 2 x 16 KB
  __shared__ __align__(16) u16 lB[2][128 * 64];   // total 64 KiB
  const int t = threadIdx.x;
  const int lane = t & 63, wv = t >> 6;        // 16 waves
  const int wm = wv >> 2, wn = wv & 3;         // 4M x 4N waves, 32x32/wave
  const int qr = lane >> 4, cl = lane & 15;

  // Round-2 mapping: each XCD-residue owns exactly one n-panel -> W L2-resident
  const int nwg = gridDim.x;
  const int sid = (blockIdx.x & 7) * (nwg >> 3) + (blockIdx.x >> 3);
  const int bm = sid % mtiles, bn = sid / mtiles;
  const int m0 = bm << 7, n0 = bn << 7;
  const int sec = (MODE == 0) ? (m0 >> 13) : 0;
  const u16* W =
      (MODE == 0) ? ((sec == 0) ? W0 : (sec == 1) ? W1 : W2) : W0;

  v4f acc[2][2];
#pragma unroll
  for (int i = 0; i < 2; ++i)
#pragma unroll
    for (int j = 0; j < 2; ++j) acc[i][j] = (v4f){0.f, 0.f, 0.f, 0.f};

  // Staging: 1024 threads x 1 chunk each per array. Thread t -> row t>>3,
  // swizzled 16B chunk (t&7)^(row&7); LDS dest linear t*16B.
  const int srow = t >> 3;
  const int swe = ((t & 7) ^ (srow & 7)) << 3;   // element offset within row
  const u16* aS = A + (size_t)(m0 + srow) * K + swe;
  const u16* bS = W + (size_t)(n0 + srow) * K + swe;

  // prologue: stage tile 0 into buf 0
  async16(aS, &lA[0][t << 3]);
  async16(bS, &lB[0][t << 3]);
  __syncthreads();

  for (int kt = 0; kt < NKT; ++kt) {
    const int cur = kt & 1;
    if (kt + 1 < NKT) {                         // stage(t+1) FIRST
      const int off = (kt + 1) << 6;
      async16(aS + off, &lA[1 - cur][t << 3]);
      async16(bS + off, &lB[1 - cur][t << 3]);
    }
    v8s a[2][2], b[2][2];
#pragma unroll
    for (int mf = 0; mf < 2; ++mf)
#pragma unroll
      for (int kh = 0; kh < 2; ++kh) {
        const int R = wm * 32 + mf * 16 + cl;
        a[mf][kh] =
            *(const v8s*)&lA[cur][R * 64 + ((((kh << 2) + qr) ^ (R & 7)) << 3)];
      }
#pragma unroll
    for (int nf = 0; nf < 2; ++nf)
#pragma unroll
      for (int kh = 0; kh < 2; ++kh) {
        const int R = wn * 32 + nf * 16 + cl;
        b[nf][kh] =
            *(const v8s*)&lB[cur][R * 64 + ((((kh << 2) + qr) ^ (R & 7)) << 3)];
      }
    __builtin_amdgcn_s_setprio(1);
#pragma unroll
    for (int kh = 0; kh < 2; ++kh)
#pragma unroll
      for (int mf = 0; mf < 2; ++mf)
#pragma unroll
        for (int nf = 0; nf < 2; ++nf)
          acc[mf][nf] = __builtin_amdgcn_mfma_f32_16x16x32_bf16(
              a[mf][kh], b[nf][kh], acc[mf][nf], 0, 0, 0);
    __builtin_amdgcn_s_setprio(0);
    __syncthreads();   // drains vmcnt(0): stage(t+1) complete; buf flip safe
  }

  // ---- epilogue ----
  if constexpr (MODE == 0) {
    u16* C = (sec == 0) ? Cq : (sec == 1) ? Ck : Cv;
#pragma unroll
    for (int mf = 0; mf < 2; ++mf)
#pragma unroll
      for (int nf = 0; nf < 2; ++nf)
#pragma unroll
        for (int r = 0; r < 4; ++r) {
          const int mloc = (m0 & 8191) + wm * 32 + mf * 16 + qr * 4 + r;
          const int n = n0 + wn * 32 + nf * 16 + cl;
          const int bb = mloc >> 11, s = mloc & (S_LEN - 1);
          const int h = n >> 6, d = n & (DHEAD - 1);
          const size_t idx =
              (sec < 2) ? (((size_t)bb * NHEADS + h) * S_LEN + s) * DHEAD + d
                        : (((size_t)bb * NHEADS + h) * DHEAD + d) * S_LEN + s;
          C[idx] = f32_bf16(acc[mf][nf][r]);
        }
  } else {
#pragma unroll
    for (int mf = 0; mf < 2; ++mf)
#pragma unroll
      for (int nf = 0; nf < 2; ++nf)
#pragma unroll
        for (int r = 0; r < 4; ++r) {
          const int m = m0 + wm * 32 + mf * 16 + qr * 4 + r;
          const int n = n0 + wn * 32 + nf * 16 + cl;
          Cf[(size_t)m * 1024 + n] = acc[mf][nf][r];
        }
  }
}

// Causal flash attention, no-max softmax. Qp/Kp: [B,H,S,D]; VpT: [B,H,D,S].
// 512 blocks x 256 threads; block = (column, pair): q-tile (15-pair) then
// (pair) -> exactly 34 K-iterations per block (perfect causal load balance).
// QUAD-buffered K/V (2 groups x 2 tiles, 80KB LDS -> 2 blocks/CU): ONE
// barrier per TWO 64-key tiles.  (R4/R5 version verbatim -- best measured.)
__global__ __launch_bounds__(256, 2) void attn_causal(
    const u16* __restrict__ Qp, const u16* __restrict__ Kp,
    const u16* __restrict__ VpT, u16* __restrict__ Out) {
  __shared__ __align__(16) u16 lK[2][2][64 * 64];  // [grp parity][slot]
  __shared__ __align__(16) u16 lV[2][2][64 * 64];  // chunk(d,kc)=d*8+(kc^(d&7))
  __shared__ __align__(16) u16 pb[4][32 * 64];     // per-wave P
  const int t = threadIdx.x;
  const int lane = t & 63, w = t >> 6;
  const int qr = lane >> 4, cl = lane & 15;
  // id = xcd + 8*(pair + 8*colgroup): all 8 pairs of 8 columns share an XCD
  const int id = blockIdx.x;
  const int col = (id & 7) + ((id >> 6) << 3);   // 0..63 = h + 16*b
  const int pair = (id >> 3) & 7;
  const int h = col & 15, b = col >> 4;
  const size_t bh = ((size_t)b * NHEADS + h) * S_LEN * DHEAD;
  const u16* Qb = Qp + bh;
  const u16* Kb = Kp + bh;
  const u16* Vb = VpT + bh;   // [d][s], row stride S_LEN

  v8s vone;
#pragma unroll
  for (int j = 0; j < 8; ++j) vone[j] = (short)0x3F80;   // bf16 1.0
  const float SC = 0.125f * 1.4426950408889634f;         // (1/8)*log2(e)

  // stage 64-key tile TILE of K and V into (GP, SL)
#define STAGE_T(TILE, GP, SL)                                                 \
  do {                                                                        \
    const int kn_ = (TILE) << 6;                                              \
    _Pragma("unroll") for (int i_ = 0; i_ < 2; ++i_) {                        \
      const int c_ = t + (i_ << 8);                                           \
      const int krow_ = c_ >> 3, kdc_ = (c_ & 7) ^ (krow_ & 7);               \
      async16(Kb + (size_t)(kn_ + krow_) * DHEAD + kdc_ * 8,                  \
              &lK[GP][SL][(w * 64 + (i_ << 8)) * 8]);                         \
      const int vd_ = c_ >> 3, vkc_ = (c_ & 7) ^ (vd_ & 7);                   \
      async16(Vb + (size_t)vd_ * S_LEN + kn_ + vkc_ * 8,                      \
              &lV[GP][SL][(w * 64 + (i_ << 8)) * 8]);                         \
    }                                                                         \
  } while (0)

  for (int phase = 0; phase < 2; ++phase) {
    const int qt = phase == 0 ? (15 - pair) : pair;   // heavy tile first
    const int q0 = qt << 7;
    const int wr0 = q0 + w * 32;   // this wave's first q-row

    v8s aq[2][2];
#pragma unroll
    for (int mf = 0; mf < 2; ++mf)
#pragma unroll
      for (int kf = 0; kf < 2; ++kf)
        aq[mf][kf] = *(const v8s*)(Qb + (size_t)(wr0 + mf * 16 + cl) * DHEAD +
                                   kf * 32 + qr * 8);

    v4f o[2][4], lac[2];
#pragma unroll
    for (int mf = 0; mf < 2; ++mf) {
      lac[mf] = (v4f){0.f, 0.f, 0.f, 0.f};
#pragma unroll
      for (int nf = 0; nf < 4; ++nf) o[mf][nf] = (v4f){0.f, 0.f, 0.f, 0.f};
    }

    const int ngrp = qt + 1;          // nkt = 2*qt+2 tiles = ngrp groups of 2
    __syncthreads();   // prior phase's LDS reads complete before re-staging
    STAGE_T(0, 0, 0);
    STAGE_T(1, 0, 1);

    for (int g = 0; g < ngrp; ++g) {
      const int gp = g & 1;
      __syncthreads();   // group g's 8 loads landed; buf[1-gp] free
      if (g + 1 < ngrp) {
        STAGE_T(2 * g + 2, 1 - gp, 0);
        STAGE_T(2 * g + 3, 1 - gp, 1);
      }
#pragma unroll
      for (int sl = 0; sl < 2; ++sl) {
        const int kt = 2 * g + sl;
        const int k0 = kt << 6;
        if (k0 > wr0 + 31) continue;   // wave-uniform: fully above diagonal
        const u16* lKc = &lK[gp][sl][0];
        const u16* lVc = &lV[gp][sl][0];

        // ---- S = Q K^T  (16 MFMA) ----
        v4f sacc[2][4];
#pragma unroll
        for (int mf = 0; mf < 2; ++mf)
#pragma unroll
          for (int ni = 0; ni < 4; ++ni) sacc[mf][ni] = (v4f){0.f, 0.f, 0.f, 0.f};
#pragma unroll
        for (int kf = 0; kf < 2; ++kf)
#pragma unroll
          for (int ni = 0; ni < 4; ++ni) {
            const v8s bk = *(const v8s*)&lKc[((ni * 16 + cl) * 8 +
                                             (((kf << 2) + qr) ^ (cl & 7))) * 8];
            sacc[0][ni] = __builtin_amdgcn_mfma_f32_16x16x32_bf16(
                aq[0][kf], bk, sacc[0][ni], 0, 0, 0);
            sacc[1][ni] = __builtin_amdgcn_mfma_f32_16x16x32_bf16(
                aq[1][kf], bk, sacc[1][ni], 0, 0, 0);
          }

        // ---- exp2, (diagonal-only) mask, truncate-to-bf16, store P ----
#pragma unroll
        for (int mf = 0; mf < 2; ++mf) {
          const int rowb0 = wr0 + mf * 16;
          if (k0 + 63 <= rowb0) {        // wave-uniform: no masking here
#pragma unroll
            for (int ni = 0; ni < 4; ++ni) {
              const int kc = ni * 2 + (cl >> 3);
#pragma unroll
              for (int r = 0; r < 4; ++r) {
                const float e = EXP2F(sacc[mf][ni][r] * SC);
                pb[w][((kc * 32 + mf * 16 + r * 4 + qr) << 3) + (cl & 7)] =
                    (u16)(__float_as_uint(e) >> 16);
              }
            }
          } else {                        // diagonal: mask then exp
            const int rowb = rowb0 + qr * 4;
#pragma unroll
            for (int ni = 0; ni < 4; ++ni) {
              const int colk = k0 + ni * 16 + cl;
              const int kc = ni * 2 + (cl >> 3);
#pragma unroll
              for (int r = 0; r < 4; ++r) {
                float e = EXP2F(sacc[mf][ni][r] * SC);
                if (colk > rowb + r) e = 0.f;
                pb[w][((kc * 32 + mf * 16 + r * 4 + qr) << 3) + (cl & 7)] =
                    (u16)(__float_as_uint(e) >> 16);
              }
            }
          }
        }

        // ---- O += P V, l += P 1  (wave-local pb: lgkmcnt ordering only) ----
#pragma unroll
        for (int kf = 0; kf < 2; ++kf) {
          const int kc = (kf << 2) + qr;
          const int sig0 = ((cl & 3) << 2) + (cl >> 2);
          const v8s ap0 = *(const v8s*)&pb[w][((kc * 32 + sig0) << 3)];
          const v8s ap1 = *(const v8s*)&pb[w][((kc * 32 + 16 + sig0) << 3)];
          lac[0] = __builtin_amdgcn_mfma_f32_16x16x32_bf16(ap0, vone, lac[0], 0, 0, 0);
          lac[1] = __builtin_amdgcn_mfma_f32_16x16x32_bf16(ap1, vone, lac[1], 0, 0, 0);
#pragma unroll
          for (int nf = 0; nf < 4; ++nf) {
            const v8s bv = *(const v8s*)&lVc[((nf * 16 + cl) * 8 +
                                             (kc ^ (cl & 7))) * 8];
            o[0][nf] = __builtin_amdgcn_mfma_f32_16x16x32_bf16(ap0, bv, o[0][nf], 0, 0, 0);
            o[1][nf] = __builtin_amdgcn_mfma_f32_16x16x32_bf16(ap1, bv, o[1][nf], 0, 0, 0);
          }
        }
      }
    }

    // epilogue: O / l
#pragma unroll
    for (int mf = 0; mf < 2; ++mf) {
      float inv[4];
#pragma unroll
      for (int r = 0; r < 4; ++r) inv[r] = 1.0f / lac[mf][r];
#pragma unroll
      for (int nf = 0; nf < 4; ++nf)
#pragma unroll
        for (int r = 0; r < 4; ++r) {
          const int row = wr0 + mf * 16 + qr * 4 + r;
          const int colo = h * DHEAD + nf * 16 + cl;
          Out[((size_t)b * S_LEN + row) * EMB + colo] = f32_bf16(o[mf][nf][r] * inv[r]);
        }
    }
  }
#undef STAGE_T
}

extern "C" void kernel_launch(void* const* d_in, const int* in_sizes, int n_in,
                              void* d_out, int out_size, void* d_ws, size_t ws_size,
                              hipStream_t stream) {
  (void)in_sizes; (void)n_in; (void)out_size; (void)ws_size;
  const float* q  = (const float*)d_in[0];
  const float* k  = (const float*)d_in[1];
  const float* v  = (const float*)d_in[2];
  // d_in[3] = causal mask (int32) — implemented analytically, not read
  const float* wq = (const float*)d_in[4];
  const float* wk = (const float*)d_in[5];
  const float* wv = (const float*)d_in[6];
  const float* wo = (const float*)d_in[7];
  float* out = (float*)d_out;   // reference output dtype is float32

  const size_t MT = (size_t)4 * S_LEN * EMB;   // 8,388,608 elems
  const size_t WT = (size_t)EMB * EMB;         // 1,048,576 elems
  u16* p = (u16*)d_ws;
  u16* xq = p; p += MT;     // xq|xk|xv contiguous: A-matrix of the fused QKV GEMM
  u16* xk = p; p += MT;
  u16* xv = p; p += MT;
  u16* wqb = p; p += WT;
  u16* wkb = p; p += WT;
  u16* wvb = p; p += WT;
  u16* wob = p; p += WT;
  u16* Qp = p; p += MT;
  u16* Kp = p; p += MT;
  u16* Vp = p; p += MT;
  u16* Ao = xq;          // xq dead after projection GEMM — reuse

  hipLaunchKernelGGL(cvt_all, dim3(512, 7), dim3(256), 0, stream,
                     (const float4*)q, (const float4*)k, (const float4*)v,
                     (const float4*)wq, (const float4*)wk, (const float4*)wv,
                     (const float4*)wo,
                     xq, xk, xv, wqb, wkb, wvb, wob,
                     (int)(MT / 8), (int)(WT / 8));
  // 192 m-tiles x 8 n-tiles = 1536 blocks; 1024 thr, 2 blocks/CU -> 3 rounds
  hipLaunchKernelGGL((gemm2ph<0>), dim3(1536), dim3(1024), 0, stream,
                     xq, wqb, wkb, wvb, Qp, Kp, Vp, (float*)nullptr, 192);
  hipLaunchKernelGGL(attn_causal, dim3(512), dim3(256), 0, stream,
                     Qp, Kp, Vp, Ao);
  // 64 m-tiles x 8 n-tiles = 512 blocks; 1024 thr, 2 blocks/CU -> 1 round
  hipLaunchKernelGGL((gemm2ph<1>), dim3(512), dim3(1024), 0, stream,
                     Ao, wob, (const u16*)nullptr, (const u16*)nullptr,
                     (u16*)nullptr, (u16*)nullptr, (u16*)nullptr, out, 64);
}